// Round 4
// baseline (324.726 us; speedup 1.0000x reference)
//
#include <hip/hip_runtime.h>
#include <hip/hip_bf16.h>

typedef short short8 __attribute__((ext_vector_type(8)));
typedef float f32x4 __attribute__((ext_vector_type(4)));
typedef unsigned uint4v __attribute__((ext_vector_type(4)));

#define NB 4
#define F 32          // F_IN == F_OUT == 32
#define EPB 512       // edges per block (old cell-sort path)
#define SCHUNK 2048   // edges per block in old sort kernels
#define MAXNBLK 1024

__device__ __forceinline__ int cell_of(float ax, float ay) {
    float tx = (ax + 1.0f) * 1.5f;
    float ty = (ay + 1.0f) * 1.5f;
    int kx = (int)tx; if (kx > 2) kx = 2; if (kx < 0) kx = 0;
    int ky = (int)ty; if (ky > 2) ky = 2; if (ky < 0) ky = 0;
    return kx * 3 + ky;
}

__device__ __forceinline__ short f2bf(float f) {   // RNE f32->bf16
    unsigned u = __float_as_uint(f);
    unsigned r = (u + 0x7FFFu + ((u >> 16) & 1u)) >> 16;
    return (short)r;
}

__device__ __forceinline__ unsigned pk2(float a, float b) {  // packed bf16 pair
    __hip_bfloat162 h = __float22bfloat162_rn(make_float2(a, b));
    union { __hip_bfloat162 h; unsigned u; } cv; cv.h = h; return cv.u;
}

// ============================ NEW PATH: bin-owner sort =====================
// key = (dst>>5)*9 + cell ; packed rec = {src u16, dstloc u16, qfx u16, qfy u16}

__global__ __launch_bounds__(256) void s1_hist(
    const int* __restrict__ ei, const float* __restrict__ attr, int E,
    int* __restrict__ keycnt)
{
    int stride = gridDim.x * blockDim.x;
    for (int e = blockIdx.x * blockDim.x + threadIdx.x; e < E; e += stride) {
        int dst = ei[e];
        float2 a = reinterpret_cast<const float2*>(attr)[e];
        atomicAdd(&keycnt[(dst >> 5) * 9 + cell_of(a.x, a.y)], 1);
    }
}

__global__ __launch_bounds__(256) void s2_scan(
    const int* __restrict__ keycnt, int* __restrict__ keybase,
    int* __restrict__ cursor, int K)
{
    __shared__ int part[256];
    int t = threadIdx.x;
    int chunk = (K + 255) / 256;
    int lo = t * chunk, hi = min(lo + chunk, K);
    int s = 0;
    for (int q = lo; q < hi; ++q) s += keycnt[q];
    part[t] = s;
    __syncthreads();
    if (t == 0) {
        int run = 0;
        for (int j = 0; j < 256; ++j) { int v = part[j]; part[j] = run; run += v; }
        keybase[K] = run;
    }
    __syncthreads();
    int run = part[t];
    for (int q = lo; q < hi; ++q) {
        int v = keycnt[q];
        keybase[q] = run; cursor[q] = run;
        run += v;
    }
}

__global__ __launch_bounds__(256) void s3_scatter(
    const int* __restrict__ ei, const float* __restrict__ attr, int E,
    int* __restrict__ cursor, uint2* __restrict__ packed)
{
    int stride = gridDim.x * blockDim.x;
    for (int e = blockIdx.x * blockDim.x + threadIdx.x; e < E; e += stride) {
        int dst = ei[e];
        int src = ei[E + e];
        float2 a = reinterpret_cast<const float2*>(attr)[e];
        float tx = (a.x + 1.0f) * 1.5f, ty = (a.y + 1.0f) * 1.5f;
        int kx = (int)tx; if (kx > 2) kx = 2; if (kx < 0) kx = 0;
        int ky = (int)ty; if (ky > 2) ky = 2; if (ky < 0) ky = 0;
        float fx = tx - kx, fy = ty - ky;
        unsigned qfx = (unsigned)(fminf(fmaxf(fx, 0.f), 1.f) * 65535.f + 0.5f);
        unsigned qfy = (unsigned)(fminf(fmaxf(fy, 0.f), 1.f) * 65535.f + 0.5f);
        int key = (dst >> 5) * 9 + kx * 3 + ky;
        int pos = atomicAdd(&cursor[key], 1);
        uint2 rec;
        rec.x = (unsigned)src | ((unsigned)(dst & 31) << 16);
        rec.y = qfx | (qfy << 16);
        packed[pos] = rec;
    }
}

// Main: 2 waves per 32-node bin; per-cell segments; direct per-lane A-fragment
// gather; LDS f32 accumulation; single non-atomic writeout per node.
__global__ __launch_bounds__(256) void bconv_seg(
    const float* __restrict__ x_j, const float* __restrict__ weight,
    const int* __restrict__ keybase, const uint2* __restrict__ packed,
    float* __restrict__ out, int N, int NBIN)
{
    __shared__ short wlds[16384];        // bf16 weights, (k,hi,n,col,j) swizzle, 32 KB
    __shared__ float acc[2][32][36];     // 2 bins x 32 nodes x 32 cols (pad 36)

    int t = threadIdx.x;
    // stage weights: global-coalesced read, LDS-scattered write
    for (int idx = t; idx < 16384; idx += 256) {
        int k = idx >> 10, rem = idx & 1023, i = rem >> 5, o = rem & 31;
        int slot = ((((k * 4 + (i >> 3)) * 2 + (o >> 4)) * 16) + (o & 15)) * 8 + (i & 7);
        wlds[slot] = f2bf(weight[idx]);
    }
    for (int idx = t; idx < 2 * 32 * 36; idx += 256)
        (&acc[0][0][0])[idx] = 0.f;
    __syncthreads();

    int wid = t >> 6, lane = t & 63;
    int binslot = wid >> 1, h = wid & 1;
    int bin = blockIdx.x * 2 + binslot;
    int row16 = lane & 15, hi = lane >> 4;

    if (bin < NBIN) {
        for (int c = 0; c < 9; ++c) {
            int key = bin * 9 + c;
            int s0 = keybase[key], s1 = keybase[key + 1];
            int len = s1 - s0;
            if (len <= 0) continue;
            int kx0 = c / 3, ky0 = c - 3 * (c / 3);

            short8 wb0[4], wb1[4];
            #pragma unroll
            for (int kk = 0; kk < 4; ++kk) {
                int ks = (kx0 + (kk >> 1)) * NB + (ky0 + (kk & 1));
                wb0[kk] = *reinterpret_cast<const short8*>(
                    &wlds[(((ks * 4 + hi) * 2 + 0) * 16 + row16) * 8]);
                wb1[kk] = *reinterpret_cast<const short8*>(
                    &wlds[(((ks * 4 + hi) * 2 + 1) * 16 + row16) * 8]);
            }

            int nt = (len + 15) >> 4;
            auto ldtile = [&](int tti, uint2& r, float4& A, float4& B, bool& v) {
                int p = s0 + tti * 16 + row16;   // lane's edge = row16
                v = p < s1;
                int pp = v ? p : s0;
                r = packed[pp];
                int src = r.x & 0xFFFF;
                const float4* x4 = reinterpret_cast<const float4*>(x_j);
                A = x4[src * 8 + 2 * hi];
                B = x4[src * 8 + 2 * hi + 1];
            };

            int ti = h;
            uint2 rec = {0, 0}; float4 fa = {0,0,0,0}, fb = {0,0,0,0}; bool val = false;
            if (ti < nt) ldtile(ti, rec, fa, fb, val);
            for (; ti < nt; ti += 2) {
                uint2 recn = rec; float4 fan = fa, fbn = fb; bool valn = false;
                if (ti + 2 < nt) ldtile(ti + 2, recn, fan, fbn, valn);

                float fx = (float)(rec.y & 0xFFFF) * (1.f / 65535.f);
                float fy = (float)(rec.y >> 16)    * (1.f / 65535.f);
                float vs = val ? 1.f : 0.f;
                float bxa = 1.f - fx, bya = 1.f - fy;
                float bc[4] = { bxa * bya * vs, bxa * fy * vs,
                                fx * bya * vs, fx * fy * vs };
                int dstloc = (rec.x >> 16) & 31;

                f32x4 a0 = {0,0,0,0}, a1 = {0,0,0,0};
                #pragma unroll
                for (int kk = 0; kk < 4; ++kk) {
                    float s = bc[kk];
                    uint4v u;
                    u[0] = pk2(fa.x * s, fa.y * s);
                    u[1] = pk2(fa.z * s, fa.w * s);
                    u[2] = pk2(fb.x * s, fb.y * s);
                    u[3] = pk2(fb.z * s, fb.w * s);
                    short8 av = __builtin_bit_cast(short8, u);
                    a0 = __builtin_amdgcn_mfma_f32_16x16x32_bf16(av, wb0[kk], a0, 0, 0, 0);
                    a1 = __builtin_amdgcn_mfma_f32_16x16x32_bf16(av, wb1[kk], a1, 0, 0, 0);
                }
                // C row r = edge 4*hi+r, col = row16 (+16)
                #pragma unroll
                for (int r = 0; r < 4; ++r) {
                    int n = __shfl(dstloc, 4 * hi + r, 64);
                    atomicAdd(&acc[binslot][n][row16],      a0[r]);
                    atomicAdd(&acc[binslot][n][16 + row16], a1[r]);
                }
                rec = recn; fa = fan; fb = fbn; val = valn;
            }
        }
    }
    __syncthreads();

    // writeout: 64 nodes x 32 cols, non-atomic
    int nloc = t >> 2, col8 = (t & 3) * 8;
    int node = blockIdx.x * 64 + nloc;
    if (node < N) {
        int bs = nloc >> 5, nn = nloc & 31;
        float4 v0 = *reinterpret_cast<float4*>(&acc[bs][nn][col8]);
        float4 v1 = *reinterpret_cast<float4*>(&acc[bs][nn][col8 + 4]);
        *reinterpret_cast<float4*>(&out[(size_t)node * F + col8])     = v0;
        *reinterpret_cast<float4*>(&out[(size_t)node * F + col8 + 4]) = v1;
    }
}

// ====================== OLD PATH (R3): cell sort + global atomics ==========

__global__ __launch_bounds__(256) void hist_kernel(
    const float* __restrict__ attr, int E, int* __restrict__ counts)
{
    __shared__ int hh[9];
    int b = blockIdx.x, t = threadIdx.x;
    if (t < 9) hh[t] = 0;
    __syncthreads();
    int start = b * SCHUNK, end = min(start + SCHUNK, E);
    for (int e = start + t; e < end; e += 256) {
        float2 a = reinterpret_cast<const float2*>(attr)[e];
        atomicAdd(&hh[cell_of(a.x, a.y)], 1);
    }
    __syncthreads();
    if (t < 9) counts[b * 9 + t] = hh[t];
}

__global__ __launch_bounds__(512) void scan_kernel(
    int* __restrict__ ws, int* __restrict__ counts, int nblk)
{
    __shared__ int s[MAXNBLK * 9];
    __shared__ int tot[9];
    __shared__ int coff[9];
    int n = nblk * 9;
    for (int i = threadIdx.x; i < n; i += 512) s[i] = counts[i];
    __syncthreads();
    if (threadIdx.x < 9) {
        int c = threadIdx.x, run = 0;
        for (int b = 0; b < nblk; ++b) {
            int v = s[b * 9 + c];
            s[b * 9 + c] = run;
            run += v;
        }
        tot[c] = run;
    }
    __syncthreads();
    if (threadIdx.x == 0) {
        int off = 0, boff = 0;
        for (int c = 0; c < 9; ++c) {
            ws[c] = off;  coff[c] = off;
            ws[16 + c] = boff;
            off  += tot[c];
            boff += (tot[c] + EPB - 1) / EPB;
        }
        ws[9] = off;
        ws[16 + 9] = boff;
    }
    __syncthreads();
    for (int i = threadIdx.x; i < n; i += 512)
        counts[i] = s[i] + coff[i % 9];
}

__global__ __launch_bounds__(256) void scatter_kernel(
    const float* __restrict__ attr, int E,
    const int* __restrict__ bases, int* __restrict__ sorted)
{
    __shared__ int cur[9];
    int b = blockIdx.x, t = threadIdx.x;
    if (t < 9) cur[t] = bases[b * 9 + t];
    __syncthreads();
    int start = b * SCHUNK, end = min(start + SCHUNK, E);
    for (int e = start + t; e < end; e += 256) {
        float2 a = reinterpret_cast<const float2*>(attr)[e];
        int c = cell_of(a.x, a.y);
        int pos = atomicAdd(&cur[c], 1);
        sorted[pos] = e;
    }
}

__global__ __launch_bounds__(256) void bconv_mfma(
    const float* __restrict__ x_j, const int* __restrict__ ei,
    const float* __restrict__ attr, const float* __restrict__ weight,
    const int* __restrict__ ws, const int* __restrict__ sorted,
    float* __restrict__ out, int E)
{
    int b = blockIdx.x;
    const int* blkoff = ws + 16;
    if (b >= blkoff[9]) return;
    int c = 0;
    #pragma unroll
    for (int q = 1; q < 9; ++q) c += (b >= blkoff[q]) ? 1 : 0;
    int kx0 = c / 3, ky0 = c - 3 * (c / 3);
    int local  = b - blkoff[c];
    int cstart = ws[c];
    int cend   = ws[c + 1];
    int pstart = cstart + local * EPB;
    int pend   = min(pstart + EPB, cend);

    int t     = threadIdx.x;
    int wid   = t >> 6;
    int lane  = t & 63;
    int row16 = lane & 15;
    int hi    = lane >> 4;

    short8 wb[4][2];
    #pragma unroll
    for (int kk = 0; kk < 4; ++kk) {
        int ks = (kx0 + (kk >> 1)) * NB + (ky0 + (kk & 1));
        const float* wp = weight + (size_t)ks * F * F;
        #pragma unroll
        for (int n = 0; n < 2; ++n) {
            short8 v;
            #pragma unroll
            for (int j = 0; j < 8; ++j)
                v[j] = f2bf(wp[(8 * hi + j) * F + row16 + 16 * n]);
            wb[kk][n] = v;
        }
    }

    int wstart = pstart + wid * (EPB / 4);
    int wend   = min(wstart + (EPB / 4), pend);
    if (wstart >= wend) return;

    auto ldt = [&](int tstart, uint2& dd, float4& A, float4& B, bool& v) {
        int p = tstart + row16;
        v = p < wend;
        int pp = v ? p : wstart;
        int e  = sorted[pp];
        dd.x = ei[e];
        float2 a = reinterpret_cast<const float2*>(attr)[e];
        dd.y = __float_as_uint(a.x);
        int srcn = ei[E + e];
        const float4* xr = reinterpret_cast<const float4*>(x_j + (size_t)srcn * F);
        A = xr[2 * hi];
        B = xr[2 * hi + 1];
        dd.x |= ((unsigned)__float_as_uint(a.y) & 0u);  // (a.y in sep var below)
        (void)a;
    };
    (void)ldt;

    int ntiles = (wend - wstart + 15) >> 4;
    // simple per-lane direct-fragment loop (no LDS staging)
    for (int tt = 0; tt < ntiles; ++tt) {
        int p = wstart + tt * 16 + row16;
        bool v = p < wend;
        int pp = v ? p : wstart;
        int e  = sorted[pp];
        int dst = ei[e];
        int srcn = ei[E + e];
        float2 a = reinterpret_cast<const float2*>(attr)[e];
        const float4* xr = reinterpret_cast<const float4*>(x_j + (size_t)srcn * F);
        float4 fa = xr[2 * hi];
        float4 fb = xr[2 * hi + 1];

        float fx = (a.x + 1.0f) * 1.5f - (float)kx0;
        float fy = (a.y + 1.0f) * 1.5f - (float)ky0;
        float vs = v ? 1.f : 0.f;
        float bxa = 1.f - fx, bya = 1.f - fy;
        float bc[4] = { bxa * bya * vs, bxa * fy * vs, fx * bya * vs, fx * fy * vs };

        f32x4 a0 = {0,0,0,0}, a1 = {0,0,0,0};
        #pragma unroll
        for (int kk = 0; kk < 4; ++kk) {
            float s = bc[kk];
            uint4v u;
            u[0] = pk2(fa.x * s, fa.y * s);
            u[1] = pk2(fa.z * s, fa.w * s);
            u[2] = pk2(fb.x * s, fb.y * s);
            u[3] = pk2(fb.z * s, fb.w * s);
            short8 av = __builtin_bit_cast(short8, u);
            a0 = __builtin_amdgcn_mfma_f32_16x16x32_bf16(av, wb[kk][0], a0, 0, 0, 0);
            a1 = __builtin_amdgcn_mfma_f32_16x16x32_bf16(av, wb[kk][1], a1, 0, 0, 0);
        }
        #pragma unroll
        for (int r = 0; r < 4; ++r) {
            int d = __shfl(v ? dst : -1, 4 * hi + r, 64);
            if (d >= 0) {
                atomicAdd(&out[(size_t)d * F + row16],      a0[r]);
                atomicAdd(&out[(size_t)d * F + 16 + row16], a1[r]);
            }
        }
    }
    (void)wid;
}

__global__ __launch_bounds__(256) void bconv_fallback(
    const float* __restrict__ x_j, const int* __restrict__ ei,
    const float* __restrict__ attr, const float* __restrict__ weight,
    float* __restrict__ out, int E)
{
    __shared__ float wl[16 * F * F];
    __shared__ float featl[8][F];
    for (int idx = threadIdx.x; idx < 4096; idx += 256)
        reinterpret_cast<float4*>(wl)[idx] = reinterpret_cast<const float4*>(weight)[idx];
    __syncthreads();

    int lane = threadIdx.x & 31, eslot = threadIdx.x >> 5;
    for (int p = blockIdx.x * 8 + eslot; p < E; p += gridDim.x * 8) {
        int dst = ei[p], srcn = ei[E + p];
        float ax = attr[2 * p], ay = attr[2 * p + 1];
        featl[eslot][lane] = x_j[(size_t)srcn * F + lane];
        float tx = (ax + 1.0f) * 1.5f, ty = (ay + 1.0f) * 1.5f;
        int kx0 = (int)tx; if (kx0 > 2) kx0 = 2; if (kx0 < 0) kx0 = 0;
        int ky0 = (int)ty; if (ky0 > 2) ky0 = 2; if (ky0 < 0) ky0 = 0;
        float fx = tx - kx0, fy = ty - ky0;
        float bcv[4] = { (1.0f - fx) * (1.0f - fy), (1.0f - fx) * fy,
                         fx * (1.0f - fy), fx * fy };
        float msg = 0.f;
        const float4* f4 = reinterpret_cast<const float4*>(&featl[eslot][0]);
        #pragma unroll
        for (int kk = 0; kk < 4; ++kk) {
            int k = (kx0 + (kk >> 1)) * NB + (ky0 + (kk & 1));
            const float* wk = wl + k * F * F;
            float acc2 = 0.f;
            #pragma unroll
            for (int j = 0; j < 8; ++j) {
                float4 f = f4[j];
                acc2 = fmaf(f.x, wk[(4 * j + 0) * F + lane], acc2);
                acc2 = fmaf(f.y, wk[(4 * j + 1) * F + lane], acc2);
                acc2 = fmaf(f.z, wk[(4 * j + 2) * F + lane], acc2);
                acc2 = fmaf(f.w, wk[(4 * j + 3) * F + lane], acc2);
            }
            msg = fmaf(bcv[kk], acc2, msg);
        }
        atomicAdd(&out[(size_t)dst * F + lane], msg);
    }
}

extern "C" void kernel_launch(void* const* d_in, const int* in_sizes, int n_in,
                              void* d_out, int out_size, void* d_ws, size_t ws_size,
                              hipStream_t stream) {
    const float* x_j    = (const float*)d_in[1];
    const int*   ei     = (const int*)d_in[2];
    const float* attr   = (const float*)d_in[3];
    const float* weight = (const float*)d_in[4];
    float* out = (float*)d_out;
    int E = in_sizes[2] / 2;
    int N = in_sizes[0] / F;

    int NBIN = (N + 31) >> 5;
    int K = NBIN * 9;
    // ws layout (new path): keycnt[K] | keybase[K+1] | cursor[K] | pad | packed[E] uint2
    size_t poff = ((size_t)(3 * K + 2) + 1) & ~(size_t)1;
    size_t need_new = (poff + 2 * (size_t)E) * sizeof(int);

    int nblk_sort = (E + SCHUNK - 1) / SCHUNK;
    int sorted_off = 32 + ((nblk_sort * 9 + 15) & ~15);
    size_t need_old = (size_t)(sorted_off + E) * sizeof(int);

    if (ws_size >= need_new && N <= 65536) {
        int* ws      = (int*)d_ws;
        int* keycnt  = ws;
        int* keybase = ws + K;
        int* cursor  = ws + 2 * K + 1;
        uint2* packed = (uint2*)(ws + poff);
        hipMemsetAsync(keycnt, 0, (size_t)K * sizeof(int), stream);
        s1_hist<<<2048, 256, 0, stream>>>(ei, attr, E, keycnt);
        s2_scan<<<1, 256, 0, stream>>>(keycnt, keybase, cursor, K);
        s3_scatter<<<2048, 256, 0, stream>>>(ei, attr, E, cursor, packed);
        int nblk_main = (NBIN + 1) / 2;
        bconv_seg<<<nblk_main, 256, 0, stream>>>(x_j, weight, keybase, packed, out, N, NBIN);
    } else if (nblk_sort <= MAXNBLK && ws_size >= need_old) {
        hipMemsetAsync(d_out, 0, (size_t)out_size * sizeof(float), stream);
        int* ws      = (int*)d_ws;
        int* counts  = ws + 32;
        int* sorted  = ws + sorted_off;
        hist_kernel<<<nblk_sort, 256, 0, stream>>>(attr, E, counts);
        scan_kernel<<<1, 512, 0, stream>>>(ws, counts, nblk_sort);
        scatter_kernel<<<nblk_sort, 256, 0, stream>>>(attr, E, counts, sorted);
        int nblk_main = (E + EPB - 1) / EPB + 9;
        bconv_mfma<<<nblk_main, 256, 0, stream>>>(x_j, ei, attr, weight, ws, sorted, out, E);
    } else {
        hipMemsetAsync(d_out, 0, (size_t)out_size * sizeof(float), stream);
        bconv_fallback<<<2048, 256, 0, stream>>>(x_j, ei, attr, weight, out, E);
    }
}

// Round 5
// 236.553 us; speedup vs baseline: 1.3727x; 1.3727x over previous
//
#include <hip/hip_runtime.h>
#include <hip/hip_bf16.h>

typedef short short8 __attribute__((ext_vector_type(8)));
typedef float f32x4 __attribute__((ext_vector_type(4)));
typedef unsigned uint4v __attribute__((ext_vector_type(4)));

#define F 32
#define NB 4
#define BINSH 6        // 64 nodes per bin
#define BINSZ 64
#define SCH 8192       // edges per scatter block
#define MAXBIN 2048

__device__ __forceinline__ short f2bf(float f) {   // RNE f32->bf16
    unsigned u = __float_as_uint(f);
    unsigned r = (u + 0x7FFFu + ((u >> 16) & 1u)) >> 16;
    return (short)r;
}

__device__ __forceinline__ unsigned pk2(float a, float b) {  // packed bf16 pair
    __hip_bfloat162 h = __float22bfloat162_rn(make_float2(a, b));
    union { __hip_bfloat162 h; unsigned u; } cv; cv.h = h; return cv.u;
}

// ---------------- sort by dst-bin (block-local hist, cursor reservation) ----

__global__ __launch_bounds__(256) void k_hist(
    const int* __restrict__ ei, int E, int nbin, int* __restrict__ keycnt)
{
    __shared__ int h[MAXBIN];
    int t = threadIdx.x;
    for (int i = t; i < nbin; i += 256) h[i] = 0;
    __syncthreads();
    int stride = gridDim.x * blockDim.x;
    for (int e = blockIdx.x * blockDim.x + t; e < E; e += stride)
        atomicAdd(&h[ei[e] >> BINSH], 1);          // LDS atomic
    __syncthreads();
    for (int i = t; i < nbin; i += 256)
        if (h[i]) atomicAdd(&keycnt[i], h[i]);     // ~nbin atomics per block
}

__global__ __launch_bounds__(256) void k_scan(
    const int* __restrict__ keycnt, int* __restrict__ keybase,
    int* __restrict__ cursor, int nbin)
{
    __shared__ int part[256];
    int t = threadIdx.x;
    int chunk = (nbin + 255) / 256;
    int lo = t * chunk, hi = min(lo + chunk, nbin);
    int s = 0;
    for (int q = lo; q < hi; ++q) s += keycnt[q];
    part[t] = s;
    __syncthreads();
    if (t == 0) {
        int run = 0;
        for (int j = 0; j < 256; ++j) { int v = part[j]; part[j] = run; run += v; }
        keybase[nbin] = run;
    }
    __syncthreads();
    int run = part[t];
    for (int q = lo; q < hi; ++q) {
        keybase[q] = run; cursor[q] = run;
        run += keycnt[q];
    }
}

// rec: x = src(u16) | dstloc(u16)<<16 ; y = qtx(u16) | qty(u16)<<16
__global__ __launch_bounds__(256) void k_scatter(
    const int* __restrict__ ei, const float* __restrict__ attr, int E, int nbin,
    int* __restrict__ cursor, uint2* __restrict__ packed)
{
    __shared__ int h[MAXBIN];
    int t = threadIdx.x, b = blockIdx.x;
    int start = b * SCH, end = min(start + SCH, E);
    for (int i = t; i < nbin; i += 256) h[i] = 0;
    __syncthreads();
    for (int e = start + t; e < end; e += 256)
        atomicAdd(&h[ei[e] >> BINSH], 1);
    __syncthreads();
    for (int k = t; k < nbin; k += 256) {
        int c = h[k];
        h[k] = c ? atomicAdd(&cursor[k], c) : 0;   // block reserves range per key
    }
    __syncthreads();
    for (int e = start + t; e < end; e += 256) {
        int dst = ei[e];
        int src = ei[E + e];
        float2 a = reinterpret_cast<const float2*>(attr)[e];
        float tx = fminf(fmaxf((a.x + 1.0f) * 1.5f, 0.f), 3.f);
        float ty = fminf(fmaxf((a.y + 1.0f) * 1.5f, 0.f), 3.f);
        unsigned qtx = (unsigned)(tx * 21845.0f + 0.5f);
        unsigned qty = (unsigned)(ty * 21845.0f + 0.5f);
        int key = dst >> BINSH;
        int pos = atomicAdd(&h[key], 1);           // LDS rank
        uint2 rec;
        rec.x = (unsigned)src | ((unsigned)(dst & (BINSZ - 1)) << 16);
        rec.y = qtx | (qty << 16);
        packed[pos] = rec;
    }
}

// ---------------- main: one block per 64-node bin, full 16-slice fold -------

__global__ __launch_bounds__(256) void bconv_bin(
    const float* __restrict__ x_j, const float* __restrict__ weight,
    const int* __restrict__ keybase, const uint2* __restrict__ packed,
    float* __restrict__ out, int N)
{
    __shared__ short wlds[16384];          // 16 slices bf16, B-frag layout, 32 KB
    __shared__ float acc[BINSZ][36];       // 9 KB, stride 36 (16B-aligned rows)

    int t = threadIdx.x;
    for (int idx = t; idx < 16384; idx += 256) {
        int k = idx >> 10, rem = idx & 1023, i = rem >> 5, o = rem & 31;
        int slot = (((k * 4 + (i >> 3)) * 2 + (o >> 4)) * 16 + (o & 15)) * 8 + (i & 7);
        wlds[slot] = f2bf(weight[idx]);
    }
    for (int idx = t; idx < BINSZ * 36; idx += 256)
        (&acc[0][0])[idx] = 0.f;
    __syncthreads();

    int bin = blockIdx.x;
    int wid = t >> 6, lane = t & 63;
    int row16 = lane & 15, hi = lane >> 4;
    int s0 = keybase[bin], s1 = keybase[bin + 1];
    int len = s1 - s0;

    if (len > 0) {
        int npair = (len + 31) >> 5;
        const float4* x4 = reinterpret_cast<const float4*>(x_j);

        uint2 cA = {0,0}, cB = {0,0}, nA = {0,0}, nB = {0,0};
        float4 cA0 = {0,0,0,0}, cA1 = cA0, cB0 = cA0, cB1 = cA0;
        float4 nA0 = cA0, nA1 = cA0, nB0 = cA0, nB1 = cA0;

        int pi = wid;
        if (pi < npair) {
            int base = s0 + pi * 32 + row16;
            cA = packed[min(base, s1 - 1)];
            cB = packed[min(base + 16, s1 - 1)];
            int sA = cA.x & 0xFFFF, sB = cB.x & 0xFFFF;
            cA0 = x4[sA * 8 + 2 * hi]; cA1 = x4[sA * 8 + 2 * hi + 1];
            cB0 = x4[sB * 8 + 2 * hi]; cB1 = x4[sB * 8 + 2 * hi + 1];
        }
        for (; pi < npair; pi += 4) {
            // prefetch pair pi+4
            if (pi + 4 < npair) {
                int base = s0 + (pi + 4) * 32 + row16;
                nA = packed[min(base, s1 - 1)];
                nB = packed[min(base + 16, s1 - 1)];
                int sA = nA.x & 0xFFFF, sB = nB.x & 0xFFFF;
                nA0 = x4[sA * 8 + 2 * hi]; nA1 = x4[sA * 8 + 2 * hi + 1];
                nB0 = x4[sB * 8 + 2 * hi]; nB1 = x4[sB * 8 + 2 * hi + 1];
            }

            int baseA = s0 + pi * 32 + row16;
            float vA = (baseA      < s1) ? 1.f : 0.f;
            float vB = (baseA + 16 < s1) ? 1.f : 0.f;
            float txA = (float)(cA.y & 0xFFFF) * (1.f / 21845.f);
            float tyA = (float)(cA.y >> 16)    * (1.f / 21845.f);
            float txB = (float)(cB.y & 0xFFFF) * (1.f / 21845.f);
            float tyB = (float)(cB.y >> 16)    * (1.f / 21845.f);
            float bxA[4], byA[4], bxB[4], byB[4];
            #pragma unroll
            for (int q = 0; q < 4; ++q) {
                bxA[q] = fmaxf(0.f, 1.f - fabsf(txA - (float)q)) * vA;
                byA[q] = fmaxf(0.f, 1.f - fabsf(tyA - (float)q));
                bxB[q] = fmaxf(0.f, 1.f - fabsf(txB - (float)q)) * vB;
                byB[q] = fmaxf(0.f, 1.f - fabsf(tyB - (float)q));
            }
            int dA = (cA.x >> 16) & (BINSZ - 1);
            int dB = (cB.x >> 16) & (BINSZ - 1);
            float flA[8] = { cA0.x, cA0.y, cA0.z, cA0.w, cA1.x, cA1.y, cA1.z, cA1.w };
            float flB[8] = { cB0.x, cB0.y, cB0.z, cB0.w, cB1.x, cB1.y, cB1.z, cB1.w };

            f32x4 aA0 = {0,0,0,0}, aA1 = aA0, aB0 = aA0, aB1 = aA0;
            #pragma unroll
            for (int kx = 0; kx < 4; ++kx) {
                #pragma unroll
                for (int ky = 0; ky < 4; ++ky) {
                    int ks = kx * 4 + ky;
                    float sA = bxA[kx] * byA[ky];
                    float sB = bxB[kx] * byB[ky];
                    short8 w0 = *reinterpret_cast<const short8*>(
                        &wlds[(((ks * 4 + hi) * 2 + 0) * 16 + row16) * 8]);
                    short8 w1 = *reinterpret_cast<const short8*>(
                        &wlds[(((ks * 4 + hi) * 2 + 1) * 16 + row16) * 8]);
                    uint4v uA, uB;
                    uA[0] = pk2(flA[0] * sA, flA[1] * sA);
                    uA[1] = pk2(flA[2] * sA, flA[3] * sA);
                    uA[2] = pk2(flA[4] * sA, flA[5] * sA);
                    uA[3] = pk2(flA[6] * sA, flA[7] * sA);
                    uB[0] = pk2(flB[0] * sB, flB[1] * sB);
                    uB[1] = pk2(flB[2] * sB, flB[3] * sB);
                    uB[2] = pk2(flB[4] * sB, flB[5] * sB);
                    uB[3] = pk2(flB[6] * sB, flB[7] * sB);
                    short8 avA = __builtin_bit_cast(short8, uA);
                    short8 avB = __builtin_bit_cast(short8, uB);
                    aA0 = __builtin_amdgcn_mfma_f32_16x16x32_bf16(avA, w0, aA0, 0, 0, 0);
                    aA1 = __builtin_amdgcn_mfma_f32_16x16x32_bf16(avA, w1, aA1, 0, 0, 0);
                    aB0 = __builtin_amdgcn_mfma_f32_16x16x32_bf16(avB, w0, aB0, 0, 0, 0);
                    aB1 = __builtin_amdgcn_mfma_f32_16x16x32_bf16(avB, w1, aB1, 0, 0, 0);
                }
            }
            // C row r = edge 4*hi+r of the tile; col = row16 (+16)
            #pragma unroll
            for (int r = 0; r < 4; ++r) {
                int nAi = __shfl(dA, 4 * hi + r, 64);
                atomicAdd(&acc[nAi][row16],      aA0[r]);
                atomicAdd(&acc[nAi][16 + row16], aA1[r]);
                int nBi = __shfl(dB, 4 * hi + r, 64);
                atomicAdd(&acc[nBi][row16],      aB0[r]);
                atomicAdd(&acc[nBi][16 + row16], aB1[r]);
            }
            cA = nA; cB = nB;
            cA0 = nA0; cA1 = nA1; cB0 = nB0; cB1 = nB1;
        }
    }
    __syncthreads();

    // writeout: 64 nodes x 32 cols, coalesced, non-atomic (zeros where no edges)
    int nloc = t >> 2, c8 = (t & 3) * 8;
    int node = bin * BINSZ + nloc;
    if (node < N) {
        float4 v0 = *reinterpret_cast<float4*>(&acc[nloc][c8]);
        float4 v1 = *reinterpret_cast<float4*>(&acc[nloc][c8 + 4]);
        *reinterpret_cast<float4*>(&out[(size_t)node * F + c8])     = v0;
        *reinterpret_cast<float4*>(&out[(size_t)node * F + c8 + 4]) = v1;
    }
}

// ---------------- fallback (no workspace): f32 VALU path --------------------

__global__ __launch_bounds__(256) void bconv_fallback(
    const float* __restrict__ x_j, const int* __restrict__ ei,
    const float* __restrict__ attr, const float* __restrict__ weight,
    float* __restrict__ out, int E)
{
    __shared__ float wl[16 * F * F];
    __shared__ float featl[8][F];
    for (int idx = threadIdx.x; idx < 4096; idx += 256)
        reinterpret_cast<float4*>(wl)[idx] = reinterpret_cast<const float4*>(weight)[idx];
    __syncthreads();

    int lane = threadIdx.x & 31, eslot = threadIdx.x >> 5;
    for (int p = blockIdx.x * 8 + eslot; p < E; p += gridDim.x * 8) {
        int dst = ei[p], srcn = ei[E + p];
        float ax = attr[2 * p], ay = attr[2 * p + 1];
        featl[eslot][lane] = x_j[(size_t)srcn * F + lane];
        float tx = (ax + 1.0f) * 1.5f, ty = (ay + 1.0f) * 1.5f;
        int kx0 = (int)tx; if (kx0 > 2) kx0 = 2; if (kx0 < 0) kx0 = 0;
        int ky0 = (int)ty; if (ky0 > 2) ky0 = 2; if (ky0 < 0) ky0 = 0;
        float fx = tx - kx0, fy = ty - ky0;
        float bcv[4] = { (1.0f - fx) * (1.0f - fy), (1.0f - fx) * fy,
                         fx * (1.0f - fy), fx * fy };
        float msg = 0.f;
        const float4* f4 = reinterpret_cast<const float4*>(&featl[eslot][0]);
        #pragma unroll
        for (int kk = 0; kk < 4; ++kk) {
            int k = (kx0 + (kk >> 1)) * NB + (ky0 + (kk & 1));
            const float* wk = wl + k * F * F;
            float a2 = 0.f;
            #pragma unroll
            for (int j = 0; j < 8; ++j) {
                float4 f = f4[j];
                a2 = fmaf(f.x, wk[(4 * j + 0) * F + lane], a2);
                a2 = fmaf(f.y, wk[(4 * j + 1) * F + lane], a2);
                a2 = fmaf(f.z, wk[(4 * j + 2) * F + lane], a2);
                a2 = fmaf(f.w, wk[(4 * j + 3) * F + lane], a2);
            }
            msg = fmaf(bcv[kk], a2, msg);
        }
        atomicAdd(&out[(size_t)dst * F + lane], msg);
    }
}

extern "C" void kernel_launch(void* const* d_in, const int* in_sizes, int n_in,
                              void* d_out, int out_size, void* d_ws, size_t ws_size,
                              hipStream_t stream) {
    const float* x_j    = (const float*)d_in[1];
    const int*   ei     = (const int*)d_in[2];
    const float* attr   = (const float*)d_in[3];
    const float* weight = (const float*)d_in[4];
    float* out = (float*)d_out;
    int E = in_sizes[2] / 2;
    int N = in_sizes[0] / F;

    int nbin = (N + BINSZ - 1) >> BINSH;
    // ws: keycnt[nbin] | keybase[nbin+1] | cursor[nbin] | pad | packed[E] uint2
    size_t poff = ((size_t)(3 * nbin + 2) + 1) & ~(size_t)1;
    size_t need = (poff + 2 * (size_t)E) * sizeof(int);

    if (nbin <= MAXBIN && N <= 65536 && ws_size >= need) {
        int* ws      = (int*)d_ws;
        int* keycnt  = ws;
        int* keybase = ws + nbin;
        int* cursor  = ws + 2 * nbin + 1;
        uint2* packed = (uint2*)(ws + poff);
        hipMemsetAsync(keycnt, 0, (size_t)nbin * sizeof(int), stream);
        k_hist<<<128, 256, 0, stream>>>(ei, E, nbin, keycnt);
        k_scan<<<1, 256, 0, stream>>>(keycnt, keybase, cursor, nbin);
        k_scatter<<<(E + SCH - 1) / SCH, 256, 0, stream>>>(ei, attr, E, nbin, cursor, packed);
        bconv_bin<<<nbin, 256, 0, stream>>>(x_j, weight, keybase, packed, out, N);
    } else {
        hipMemsetAsync(d_out, 0, (size_t)out_size * sizeof(float), stream);
        bconv_fallback<<<2048, 256, 0, stream>>>(x_j, ei, attr, weight, out, E);
    }
}